// Round 3
// baseline (65.786 us; speedup 1.0000x reference)
//
#include <hip/hip_runtime.h>

#define SB 4096
#define BB 16
#define CC 512
#define KCAP 64

struct Small {
  int   fl_old[BB];
  int   fl_new[BB];
  float scale[BB];
  int   T0;
  int   flag_u8;
};

struct Pair { int i; float w; };

// K1: per-batch parallel cumsum (one 256-thread block per batch).
// Also: zeros the cnt array, detects mask dtype (uint8 vs int32) per-block,
// computes feat_len_old and T0 (atomicMax; poison 0xAAAAAAAA is negative, safe).
__global__ void __launch_bounds__(256)
k_scan(const float* __restrict__ alphas, const void* __restrict__ mask,
       float* __restrict__ csum, Small* sm, int* __restrict__ cnt, int ncnt) {
  int b = blockIdx.x;
  int t = threadIdx.x;
  // zero per-row counters (16 blocks x 256 threads cover ncnt)
  for (int idx = b * 256 + t; idx < ncnt; idx += BB * 256) cnt[idx] = 0;
  // mask dtype detection: first 16384 words safe under either interpretation.
  // uint8 bool runs produce words like 0x01010101 > 1; int32 bools are 0/1.
  // (All-false mask is identical under both interpretations.)
  __shared__ int s_flag;
  if (t == 0) s_flag = 0;
  __syncthreads();
  const unsigned* mw_ = (const unsigned*)mask;
  unsigned bad = 0;
  for (int i = t; i < 16384; i += 256) bad |= (mw_[i] > 1u) ? 1u : 0u;
  if (bad) atomicOr(&s_flag, 1);
  __syncthreads();
  int flag = s_flag;
  if (b == 0 && t == 0) sm->flag_u8 = flag;

  int lane = t & 63, wid = t >> 6;
  int base = t * 16;
  const float* ab = alphas + b * SB + base;
  float av[16];
#pragma unroll
  for (int k = 0; k < 16; k += 4) {
    float4 v = *(const float4*)(ab + k);
    av[k] = v.x; av[k + 1] = v.y; av[k + 2] = v.z; av[k + 3] = v.w;
  }
  if (flag) {
    const unsigned char* mb = (const unsigned char*)mask + b * SB + base;
    uint4 mv = *(const uint4*)mb;
    unsigned mw[4] = {mv.x, mv.y, mv.z, mv.w};
#pragma unroll
    for (int k = 0; k < 16; ++k)
      if ((mw[k >> 2] >> ((k & 3) * 8)) & 0xFFu) av[k] = 0.f;
  } else {
    const int* mi = (const int*)mask + b * SB + base;
#pragma unroll
    for (int k = 0; k < 16; ++k)
      if (mi[k]) av[k] = 0.f;
  }
  float s = 0.f;
#pragma unroll
  for (int k = 0; k < 16; ++k) s += av[k];
  float si = s;
#pragma unroll
  for (int off = 1; off < 64; off <<= 1) {
    float v = __shfl_up(si, off);
    if (lane >= off) si += v;
  }
  __shared__ float wsum[4];
  if (lane == 63) wsum[wid] = si;
  __syncthreads();
  float woff = 0.f;
  for (int w = 0; w < wid; ++w) woff += wsum[w];
  float c = woff + (si - s);  // exclusive prefix
  float* cb = csum + b * SB + base;
#pragma unroll
  for (int k = 0; k < 16; ++k) { c += av[k]; cb[k] = c; }
  if (t == 255) {
    float total = woff + si;
    int fl = (int)floorf(total);
    sm->fl_old[b] = fl;
    atomicMax(&sm->T0, fl);
  }
}

// K2: weights + scatter-append (w != 0 only) into per-(b,t) lists;
// in-block tail reduction -> extend decision, scale, fl_new, feat_lengths out.
__global__ void __launch_bounds__(256)
k_weights(const float* __restrict__ alphas, const void* __restrict__ mask,
          const float* __restrict__ csum, Small* sm,
          int* __restrict__ cnt, Pair* __restrict__ pairs,
          float* __restrict__ out1, int T) {
  int b = blockIdx.x;
  int t = threadIdx.x;
  int T0 = sm->T0;
  int flag = sm->flag_u8;
  int fl = sm->fl_old[b];
  int base = t * 16;
  int gbase = b * SB + base;
  int rows = T + 2;
  int cntb = b * rows;

  float cs[16];
#pragma unroll
  for (int k = 0; k < 16; k += 4) {
    float4 v = *(const float4*)(csum + gbase + k);
    cs[k] = v.x; cs[k + 1] = v.y; cs[k + 2] = v.z; cs[k + 3] = v.w;
  }
  float cprev = (base == 0) ? 0.f : csum[gbase - 1];
  float av[16];
#pragma unroll
  for (int k = 0; k < 16; k += 4) {
    float4 v = *(const float4*)(alphas + gbase + k);
    av[k] = v.x; av[k + 1] = v.y; av[k + 2] = v.z; av[k + 3] = v.w;
  }
  if (flag) {
    const unsigned char* mb = (const unsigned char*)mask + gbase;
    uint4 mv = *(const uint4*)mb;
    unsigned mw[4] = {mv.x, mv.y, mv.z, mv.w};
#pragma unroll
    for (int k = 0; k < 16; ++k)
      if ((mw[k >> 2] >> ((k & 3) * 8)) & 0xFFu) av[k] = 0.f;
  } else {
    const int* mi = (const int*)mask + gbase;
#pragma unroll
    for (int k = 0; k < 16; ++k)
      if (mi[k]) av[k] = 0.f;
  }

  float tc = 0.f;
  int p = (base == 0) ? 0 : min((int)rintf(cprev), T0);
#pragma unroll
  for (int k = 0; k < 16; ++k) {
    int r = min((int)rintf(cs[k]), T0);
    int fire = r - p;
    float rwv = (fire > 0) ? (cs[k] - (float)r) : 0.f;
    int extra = fire - 1; if (extra < 0) extra = 0;
    float lwv = (av[k] - rwv) - (float)extra; // BETA = 1
    int i = base + k;
    if (rwv != 0.f) {
      int s = atomicAdd(&cnt[cntb + r], 1);
      if (s < KCAP) pairs[(size_t)(cntb + r) * KCAP + s] = Pair{i, rwv};
    }
    if (lwv != 0.f) {
      int s = atomicAdd(&cnt[cntb + p], 1);
      if (s < KCAP) pairs[(size_t)(cntb + p) * KCAP + s] = Pair{i, lwv};
    }
    for (int e = 1; e < fire; ++e) { // extra fires (never for alpha<1, kept for safety)
      int tgt = min(p + e, T0);
      int s = atomicAdd(&cnt[cntb + tgt], 1);
      if (s < KCAP) pairs[(size_t)(cntb + tgt) * KCAP + s] = Pair{i, 1.0f};
    }
    tc += ((r == fl) ? rwv : 0.f) + ((p == fl) ? lwv : 0.f);
    p = r;
  }
  // block-reduce tail contribution
  for (int off = 32; off; off >>= 1) tc += __shfl_down(tc, off);
  __shared__ float red[4];
  int wid = t >> 6;
  if ((t & 63) == 0) red[wid] = tc;
  __syncthreads();
  if (t == 0) {
    float tail = red[0] + red[1] + red[2] + red[3];
    int e = (tail >= 0.5f) ? 1 : 0;
    sm->scale[b] = e ? (1.0f / tail) : 1.0f;
    int fln = fl + e;
    sm->fl_new[b] = fln;
    out1[b] = (float)max(fln, 1);
  }
}

// K3: gather per output row (b, t) from its contribution list.
__global__ void __launch_bounds__(128)
k_gather(const float* __restrict__ src, const int* __restrict__ cnt,
         const Pair* __restrict__ pairs, const Small* __restrict__ sm,
         float* __restrict__ out, int T) {
  int t = blockIdx.x;
  int b = blockIdx.y;
  int tid = threadIdx.x;
  float4* orow = (float4*)(out + ((size_t)(b * T + t)) * CC) + tid;
  int fln = sm->fl_new[b];
  if (t >= fln) { *orow = make_float4(0.f, 0.f, 0.f, 0.f); return; }
  float m = (t < sm->fl_old[b]) ? 1.0f : sm->scale[b];
  int rows = T + 2;
  int cidx = b * rows + t;
  int n = min(cnt[cidx], KCAP);
  const Pair* pl = pairs + (size_t)cidx * KCAP;
  const float* srcb = src + (size_t)b * SB * CC;
  float4 acc = make_float4(0.f, 0.f, 0.f, 0.f);
  for (int j = 0; j < n; ++j) {
    Pair pr = pl[j];
    float4 s = ((const float4*)(srcb + (size_t)pr.i * CC))[tid];
    acc.x = fmaf(pr.w, s.x, acc.x);
    acc.y = fmaf(pr.w, s.y, acc.y);
    acc.z = fmaf(pr.w, s.z, acc.z);
    acc.w = fmaf(pr.w, s.w, acc.w);
  }
  acc.x *= m; acc.y *= m; acc.z *= m; acc.w *= m;
  *orow = acc;
}

extern "C" void kernel_launch(void* const* d_in, const int* in_sizes, int n_in,
                              void* d_out, int out_size, void* d_ws, size_t ws_size,
                              hipStream_t stream) {
  const float* src = (const float*)d_in[0];
  const void* mask = d_in[1];
  const float* alphas = (const float*)d_in[2];
  float* out = (float*)d_out;
  char* ws = (char*)d_ws;

  int T = (out_size - BB) / (BB * CC);
  int rows = T + 2;

  float* csum = (float*)(ws + 0);            // 256 KB
  Small* sm   = (Small*)(ws + 262144);       // small
  int* cnt    = (int*)(ws + 270336);         // BB*rows*4  (<= ~132 KB)
  Pair* pairs = (Pair*)(ws + 1048576);       // BB*rows*KCAP*8 (<= ~17 MB, ws is 512 MiB)

  k_scan<<<BB, 256, 0, stream>>>(alphas, mask, csum, sm, cnt, BB * rows);
  k_weights<<<BB, 256, 0, stream>>>(alphas, mask, csum, sm, cnt, pairs,
                                    out + (size_t)BB * T * CC, T);
  dim3 g(T, BB);
  k_gather<<<g, 128, 0, stream>>>(src, cnt, pairs, sm, out, T);
}

// Round 4
// 50.888 us; speedup vs baseline: 1.2927x; 1.2927x over previous
//
#include <hip/hip_runtime.h>

#define SB 4096
#define BB 16
#define CC 512

struct Small {
  int   fl_old[BB];
  int   fl_new[BB];
  float scale[BB];
  int   flag_u8;
};

// K1: per-batch parallel cumsum (one 256-thread block per batch).
// Writes csum, fl_old[b]; block 0 also writes mask-dtype flag.
__global__ void __launch_bounds__(256)
k_scan(const float* __restrict__ alphas, const void* __restrict__ mask,
       float* __restrict__ csum, Small* sm) {
  int b = blockIdx.x;
  int t = threadIdx.x;
  // mask dtype detection: first 16384 words safe under either interpretation.
  __shared__ int s_flag;
  if (t == 0) s_flag = 0;
  __syncthreads();
  const unsigned* mw_ = (const unsigned*)mask;
  unsigned bad = 0;
  for (int i = t; i < 16384; i += 256) bad |= (mw_[i] > 1u) ? 1u : 0u;
  if (bad) atomicOr(&s_flag, 1);
  __syncthreads();
  int flag = s_flag;
  if (b == 0 && t == 0) sm->flag_u8 = flag;

  int lane = t & 63, wid = t >> 6;
  int base = t * 16;
  const float* ab = alphas + b * SB + base;
  float av[16];
#pragma unroll
  for (int k = 0; k < 16; k += 4) {
    float4 v = *(const float4*)(ab + k);
    av[k] = v.x; av[k + 1] = v.y; av[k + 2] = v.z; av[k + 3] = v.w;
  }
  if (flag) {
    const unsigned char* mb = (const unsigned char*)mask + b * SB + base;
    uint4 mv = *(const uint4*)mb;
    unsigned mw[4] = {mv.x, mv.y, mv.z, mv.w};
#pragma unroll
    for (int k = 0; k < 16; ++k)
      if ((mw[k >> 2] >> ((k & 3) * 8)) & 0xFFu) av[k] = 0.f;
  } else {
    const int* mi = (const int*)mask + b * SB + base;
#pragma unroll
    for (int k = 0; k < 16; ++k)
      if (mi[k]) av[k] = 0.f;
  }
  float s = 0.f;
#pragma unroll
  for (int k = 0; k < 16; ++k) s += av[k];
  float si = s;
#pragma unroll
  for (int off = 1; off < 64; off <<= 1) {
    float v = __shfl_up(si, off);
    if (lane >= off) si += v;
  }
  __shared__ float wsum[4];
  if (lane == 63) wsum[wid] = si;
  __syncthreads();
  float woff = 0.f;
  for (int w = 0; w < wid; ++w) woff += wsum[w];
  float c = woff + (si - s);  // exclusive prefix
  float* cb = csum + b * SB + base;
#pragma unroll
  for (int k = 0; k < 16; ++k) { c += av[k]; cb[k] = c; }
  if (t == 255) {
    float total = woff + si;
    sm->fl_old[b] = (int)floorf(total);
  }
}

// K2: weights (float2 {lw, rw} per element), fire-position scatter S[b][r]=i
// (plain stores, no atomics), llast, tail reduction -> scale/fl_new/out1.
__global__ void __launch_bounds__(256)
k_weights(const float* __restrict__ alphas, const void* __restrict__ mask,
          const float* __restrict__ csum, Small* sm,
          float2* __restrict__ wlr, int* __restrict__ S,
          float* __restrict__ out1, int T) {
  int b = blockIdx.x;
  int t = threadIdx.x;
  int flag = sm->flag_u8;
  int T0 = sm->fl_old[0];
#pragma unroll
  for (int j = 1; j < BB; ++j) T0 = max(T0, sm->fl_old[j]);
  int fl = sm->fl_old[b];
  int base = t * 16;
  int gbase = b * SB + base;

  float cs[16];
#pragma unroll
  for (int k = 0; k < 16; k += 4) {
    float4 v = *(const float4*)(csum + gbase + k);
    cs[k] = v.x; cs[k + 1] = v.y; cs[k + 2] = v.z; cs[k + 3] = v.w;
  }
  float cprev = (base == 0) ? 0.f : csum[gbase - 1];
  float av[16];
#pragma unroll
  for (int k = 0; k < 16; k += 4) {
    float4 v = *(const float4*)(alphas + gbase + k);
    av[k] = v.x; av[k + 1] = v.y; av[k + 2] = v.z; av[k + 3] = v.w;
  }
  unsigned mbits = 0;
  if (flag) {
    const unsigned char* mb = (const unsigned char*)mask + gbase;
    uint4 mv = *(const uint4*)mb;
    unsigned mw[4] = {mv.x, mv.y, mv.z, mv.w};
#pragma unroll
    for (int k = 0; k < 16; ++k)
      if ((mw[k >> 2] >> ((k & 3) * 8)) & 0xFFu) { av[k] = 0.f; mbits |= 1u << k; }
  } else {
    const int* mi = (const int*)mask + gbase;
#pragma unroll
    for (int k = 0; k < 16; ++k)
      if (mi[k]) { av[k] = 0.f; mbits |= 1u << k; }
  }

  int lmax = -1;
#pragma unroll
  for (int k = 0; k < 16; ++k) if (!((mbits >> k) & 1u)) lmax = base + k;

  float tc = 0.f;
  float2 w2[16];
  int   rr[16];
  unsigned fbits = 0;
  int p = (base == 0) ? 0 : min((int)rintf(cprev), T0);
#pragma unroll
  for (int k = 0; k < 16; ++k) {
    int r = min((int)rintf(cs[k]), T0);
    int fire = r - p;                       // in {0,1} for alphas < 1
    float rwv = (fire > 0) ? (cs[k] - (float)r) : 0.f;
    float lwv = av[k] - rwv;                // extra == 0 (BETA=1, alpha<1)
    w2[k] = make_float2(lwv, rwv);
    rr[k] = r;
    if (fire > 0) fbits |= 1u << k;
    tc += ((r == fl) ? rwv : 0.f) + ((p == fl) ? lwv : 0.f);
    p = r;
  }
#pragma unroll
  for (int k = 0; k < 16; k += 2) {
    float4 st = make_float4(w2[k].x, w2[k].y, w2[k + 1].x, w2[k + 1].y);
    *(float4*)(wlr + gbase + k) = st;
  }

  // block reductions: max lmax, sum tc
  for (int off = 32; off; off >>= 1) {
    lmax = max(lmax, __shfl_down(lmax, off));
    tc += __shfl_down(tc, off);
  }
  __shared__ int   redl[4];
  __shared__ float redt[4];
  int wid = t >> 6;
  if ((t & 63) == 0) { redl[wid] = lmax; redt[wid] = tc; }
  __syncthreads();
  int llast = max(max(redl[0], redl[1]), max(redl[2], redl[3]));

  // init S rows for this batch, then scatter fire positions
  int* Sb = S + b * (T + 2);
  for (int j = t; j < T + 2; j += 256) Sb[j] = (j == 0) ? 0 : llast;
  __syncthreads();
#pragma unroll
  for (int k = 0; k < 16; ++k)
    if ((fbits >> k) & 1u) Sb[rr[k]] = base + k;

  if (t == 0) {
    float tail = redt[0] + redt[1] + redt[2] + redt[3];
    int e = (tail >= 0.5f) ? 1 : 0;
    sm->scale[b] = e ? (1.0f / tail) : 1.0f;
    int fln = fl + e;
    sm->fl_new[b] = fln;
    out1[b] = (float)max(fln, 1);
  }
}

// K3: gather per output row (b, t): contributors are exactly [S[t], S[t+1]].
__global__ void __launch_bounds__(128)
k_gather(const float* __restrict__ src, const float2* __restrict__ wlr,
         const int* __restrict__ S, const Small* __restrict__ sm,
         float* __restrict__ out, int T) {
  int t = blockIdx.x;
  int b = blockIdx.y;
  int tid = threadIdx.x;
  float4* orow = (float4*)(out + ((size_t)(b * T + t)) * CC) + tid;
  int fln = sm->fl_new[b];
  if (t >= fln) { *orow = make_float4(0.f, 0.f, 0.f, 0.f); return; }
  float m = (t < sm->fl_old[b]) ? 1.0f : sm->scale[b];
  const int* Sb = S + b * (T + 2);
  int start = Sb[t];
  int end   = Sb[t + 1];
  const float* srcb = src + (size_t)b * SB * CC;
  const float2* wb = wlr + b * SB;
  float4 acc = make_float4(0.f, 0.f, 0.f, 0.f);
  for (int i = start; i <= end; ++i) {
    float2 w2 = wb[i];
    float w = (t > 0 && i == start) ? w2.y : w2.x;  // firer -> rw, else lw
    if (w != 0.f) {
      float4 s = ((const float4*)(srcb + (size_t)i * CC))[tid];
      acc.x = fmaf(w, s.x, acc.x);
      acc.y = fmaf(w, s.y, acc.y);
      acc.z = fmaf(w, s.z, acc.z);
      acc.w = fmaf(w, s.w, acc.w);
    }
  }
  acc.x *= m; acc.y *= m; acc.z *= m; acc.w *= m;
  *orow = acc;
}

extern "C" void kernel_launch(void* const* d_in, const int* in_sizes, int n_in,
                              void* d_out, int out_size, void* d_ws, size_t ws_size,
                              hipStream_t stream) {
  const float* src = (const float*)d_in[0];
  const void* mask = d_in[1];
  const float* alphas = (const float*)d_in[2];
  float* out = (float*)d_out;
  char* ws = (char*)d_ws;

  int T = (out_size - BB) / (BB * CC);

  float* csum = (float*)(ws + 0);          // 256 KB
  float2* wlr = (float2*)(ws + 262144);    // 512 KB
  int* S      = (int*)(ws + 786432);       // BB*(T+2)*4 (~125 KB)
  Small* sm   = (Small*)(ws + 1572864);

  k_scan<<<BB, 256, 0, stream>>>(alphas, mask, csum, sm);
  k_weights<<<BB, 256, 0, stream>>>(alphas, mask, csum, sm, wlr, S,
                                    out + (size_t)BB * T * CC, T);
  dim3 g(T, BB);
  k_gather<<<g, 128, 0, stream>>>(src, wlr, S, sm, out, T);
}

// Round 5
// 48.759 us; speedup vs baseline: 1.3492x; 1.0437x over previous
//
#include <hip/hip_runtime.h>

#define SB 4096
#define BB 16
#define CC 512
#define RPB 4

struct Small {
  int   fl_old[BB];
  int   fl_new[BB];
  float scale[BB];
  int   flag_u8;
};

// K1: per-batch parallel cumsum (one 256-thread block per batch).
__global__ void __launch_bounds__(256)
k_scan(const float* __restrict__ alphas, const void* __restrict__ mask,
       float* __restrict__ csum, Small* sm) {
  int b = blockIdx.x;
  int t = threadIdx.x;
  __shared__ int s_flag;
  if (t == 0) s_flag = 0;
  __syncthreads();
  const unsigned* mw_ = (const unsigned*)mask;
  unsigned bad = 0;
  for (int i = t; i < 16384; i += 256) bad |= (mw_[i] > 1u) ? 1u : 0u;
  if (bad) atomicOr(&s_flag, 1);
  __syncthreads();
  int flag = s_flag;
  if (b == 0 && t == 0) sm->flag_u8 = flag;

  int lane = t & 63, wid = t >> 6;
  int base = t * 16;
  const float* ab = alphas + b * SB + base;
  float av[16];
#pragma unroll
  for (int k = 0; k < 16; k += 4) {
    float4 v = *(const float4*)(ab + k);
    av[k] = v.x; av[k + 1] = v.y; av[k + 2] = v.z; av[k + 3] = v.w;
  }
  if (flag) {
    const unsigned char* mb = (const unsigned char*)mask + b * SB + base;
    uint4 mv = *(const uint4*)mb;
    unsigned mw[4] = {mv.x, mv.y, mv.z, mv.w};
#pragma unroll
    for (int k = 0; k < 16; ++k)
      if ((mw[k >> 2] >> ((k & 3) * 8)) & 0xFFu) av[k] = 0.f;
  } else {
    const int* mi = (const int*)mask + b * SB + base;
#pragma unroll
    for (int k = 0; k < 16; ++k)
      if (mi[k]) av[k] = 0.f;
  }
  float s = 0.f;
#pragma unroll
  for (int k = 0; k < 16; ++k) s += av[k];
  float si = s;
#pragma unroll
  for (int off = 1; off < 64; off <<= 1) {
    float v = __shfl_up(si, off);
    if (lane >= off) si += v;
  }
  __shared__ float wsum[4];
  if (lane == 63) wsum[wid] = si;
  __syncthreads();
  float woff = 0.f;
  for (int w = 0; w < wid; ++w) woff += wsum[w];
  float c = woff + (si - s);  // exclusive prefix
  float* cb = csum + b * SB + base;
#pragma unroll
  for (int k = 0; k < 16; ++k) { c += av[k]; cb[k] = c; }
  if (t == 255) {
    float total = woff + si;
    sm->fl_old[b] = (int)floorf(total);
  }
}

// K2: weights {lw, rw}, fire-position scatter S[b][r]=i (plain stores),
// tail reduction -> scale/fl_new/feat_lengths out.
__global__ void __launch_bounds__(256)
k_weights(const float* __restrict__ alphas, const void* __restrict__ mask,
          const float* __restrict__ csum, Small* sm,
          float2* __restrict__ wlr, int* __restrict__ S,
          float* __restrict__ out1, int T) {
  int b = blockIdx.x;
  int t = threadIdx.x;
  int flag = sm->flag_u8;
  int T0 = sm->fl_old[0];
#pragma unroll
  for (int j = 1; j < BB; ++j) T0 = max(T0, sm->fl_old[j]);
  int fl = sm->fl_old[b];
  int base = t * 16;
  int gbase = b * SB + base;

  float cs[16];
#pragma unroll
  for (int k = 0; k < 16; k += 4) {
    float4 v = *(const float4*)(csum + gbase + k);
    cs[k] = v.x; cs[k + 1] = v.y; cs[k + 2] = v.z; cs[k + 3] = v.w;
  }
  float cprev = (base == 0) ? 0.f : csum[gbase - 1];
  float av[16];
#pragma unroll
  for (int k = 0; k < 16; k += 4) {
    float4 v = *(const float4*)(alphas + gbase + k);
    av[k] = v.x; av[k + 1] = v.y; av[k + 2] = v.z; av[k + 3] = v.w;
  }
  unsigned mbits = 0;
  if (flag) {
    const unsigned char* mb = (const unsigned char*)mask + gbase;
    uint4 mv = *(const uint4*)mb;
    unsigned mw[4] = {mv.x, mv.y, mv.z, mv.w};
#pragma unroll
    for (int k = 0; k < 16; ++k)
      if ((mw[k >> 2] >> ((k & 3) * 8)) & 0xFFu) { av[k] = 0.f; mbits |= 1u << k; }
  } else {
    const int* mi = (const int*)mask + gbase;
#pragma unroll
    for (int k = 0; k < 16; ++k)
      if (mi[k]) { av[k] = 0.f; mbits |= 1u << k; }
  }

  int lmax = -1;
#pragma unroll
  for (int k = 0; k < 16; ++k) if (!((mbits >> k) & 1u)) lmax = base + k;

  float tc = 0.f;
  float2 w2[16];
  int   rr[16];
  unsigned fbits = 0;
  int p = (base == 0) ? 0 : min((int)rintf(cprev), T0);
#pragma unroll
  for (int k = 0; k < 16; ++k) {
    int r = min((int)rintf(cs[k]), T0);
    int fire = r - p;                       // in {0,1} for alphas < 1
    float rwv = (fire > 0) ? (cs[k] - (float)r) : 0.f;
    float lwv = av[k] - rwv;
    w2[k] = make_float2(lwv, rwv);
    rr[k] = r;
    if (fire > 0) fbits |= 1u << k;
    tc += ((r == fl) ? rwv : 0.f) + ((p == fl) ? lwv : 0.f);
    p = r;
  }
#pragma unroll
  for (int k = 0; k < 16; k += 2) {
    float4 st = make_float4(w2[k].x, w2[k].y, w2[k + 1].x, w2[k + 1].y);
    *(float4*)(wlr + gbase + k) = st;
  }

  for (int off = 32; off; off >>= 1) {
    lmax = max(lmax, __shfl_down(lmax, off));
    tc += __shfl_down(tc, off);
  }
  __shared__ int   redl[4];
  __shared__ float redt[4];
  int wid = t >> 6;
  if ((t & 63) == 0) { redl[wid] = lmax; redt[wid] = tc; }
  __syncthreads();
  int llast = max(max(redl[0], redl[1]), max(redl[2], redl[3]));

  int* Sb = S + b * (T + 2);
  for (int j = t; j < T + 2; j += 256) Sb[j] = (j == 0) ? 0 : llast;
  __syncthreads();
#pragma unroll
  for (int k = 0; k < 16; ++k)
    if ((fbits >> k) & 1u) Sb[rr[k]] = base + k;

  if (t == 0) {
    float tail = redt[0] + redt[1] + redt[2] + redt[3];
    int e = (tail >= 0.5f) ? 1 : 0;
    sm->scale[b] = e ? (1.0f / tail) : 1.0f;
    int fln = fl + e;
    sm->fl_new[b] = fln;
    out1[b] = (float)max(fln, 1);
  }
}

// K3: gather, RPB consecutive rows per block; XCD-chunked bijective swizzle.
__global__ void __launch_bounds__(128)
k_gather(const float* __restrict__ src, const float2* __restrict__ wlr,
         const int* __restrict__ S, const Small* __restrict__ sm,
         float* __restrict__ out, int T, int nwgx, int q, int rmod) {
  // bijective chunked XCD swizzle (m204): consecutive wg stay on one XCD.
  int orig = blockIdx.x;
  int xcd = orig & 7;
  int idx = orig >> 3;
  int wg = ((xcd < rmod) ? xcd * (q + 1) : rmod * (q + 1) + (xcd - rmod) * q) + idx;
  int b  = wg / nwgx;
  int t0 = (wg - b * nwgx) * RPB;

  int tid = threadIdx.x;
  int fln = sm->fl_new[b];
  int flo = sm->fl_old[b];
  float sc = sm->scale[b];
  float* outb = out + ((size_t)b * T + t0) * CC;

  int nrows = T - t0; if (nrows > RPB) nrows = RPB;
  int nact = fln - t0; if (nact > RPB) nact = RPB; if (nact < 0) nact = 0;
  for (int j = nact; j < nrows; ++j)
    ((float4*)(outb + (size_t)j * CC))[tid] = make_float4(0.f, 0.f, 0.f, 0.f);
  if (nact <= 0) return;

  const int* Sb = S + b * (T + 2);
  int sarr[RPB + 1];
#pragma unroll
  for (int j = 0; j <= RPB; ++j) sarr[j] = (j <= nact) ? Sb[t0 + j] : 0x7FFFFFFF;

  int start = sarr[0];
  int end   = sarr[nact];
  const float* srcb = src + (size_t)b * SB * CC;
  const float2* wb  = wlr + b * SB;

  float4 acc[RPB];
#pragma unroll
  for (int j = 0; j < RPB; ++j) acc[j] = make_float4(0.f, 0.f, 0.f, 0.f);

  for (int i = start; i <= end; ++i) {
    float2 w2 = wb[i];
    float4 s = ((const float4*)(srcb + (size_t)i * CC))[tid];
#pragma unroll
    for (int j = 0; j < RPB; ++j) {
      if (j < nact) {
        bool inr = (i >= sarr[j]) && (i <= sarr[j + 1]);
        float w = (i == sarr[j] && (t0 + j) > 0) ? w2.y : w2.x;
        if (inr && w != 0.f) {
          acc[j].x = fmaf(w, s.x, acc[j].x);
          acc[j].y = fmaf(w, s.y, acc[j].y);
          acc[j].z = fmaf(w, s.z, acc[j].z);
          acc[j].w = fmaf(w, s.w, acc[j].w);
        }
      }
    }
  }
#pragma unroll
  for (int j = 0; j < RPB; ++j) {
    if (j < nact) {
      float m = ((t0 + j) == flo) ? sc : 1.0f;
      float4 v = make_float4(acc[j].x * m, acc[j].y * m, acc[j].z * m, acc[j].w * m);
      ((float4*)(outb + (size_t)j * CC))[tid] = v;
    }
  }
}

extern "C" void kernel_launch(void* const* d_in, const int* in_sizes, int n_in,
                              void* d_out, int out_size, void* d_ws, size_t ws_size,
                              hipStream_t stream) {
  const float* src = (const float*)d_in[0];
  const void* mask = d_in[1];
  const float* alphas = (const float*)d_in[2];
  float* out = (float*)d_out;
  char* ws = (char*)d_ws;

  int T = (out_size - BB) / (BB * CC);

  float* csum = (float*)(ws + 0);          // 256 KB
  float2* wlr = (float2*)(ws + 262144);    // 512 KB
  int* S      = (int*)(ws + 786432);       // BB*(T+2)*4
  Small* sm   = (Small*)(ws + 1572864);

  k_scan<<<BB, 256, 0, stream>>>(alphas, mask, csum, sm);
  k_weights<<<BB, 256, 0, stream>>>(alphas, mask, csum, sm, wlr, S,
                                    out + (size_t)BB * T * CC, T);
  int nwgx = (T + RPB - 1) / RPB;
  int nwg = BB * nwgx;
  int q = nwg / 8, rmod = nwg % 8;
  k_gather<<<nwg, 128, 0, stream>>>(src, wlr, S, sm, out, T, nwgx, q, rmod);
}

// Round 6
// 47.809 us; speedup vs baseline: 1.3760x; 1.0199x over previous
//
#include <hip/hip_runtime.h>

#define SB 4096
#define BB 16
#define CC 512
#define RPB 4
#define CH 8

struct Small {
  int   fl_old[BB];
  int   fl_new[BB];
  float scale[BB];
  int   flag_u8;
};

// K1: per-batch parallel cumsum (one 256-thread block per batch).
__global__ void __launch_bounds__(256)
k_scan(const float* __restrict__ alphas, const void* __restrict__ mask,
       float* __restrict__ csum, Small* sm) {
  int b = blockIdx.x;
  int t = threadIdx.x;
  __shared__ int s_flag;
  if (t == 0) s_flag = 0;
  __syncthreads();
  const unsigned* mw_ = (const unsigned*)mask;
  unsigned bad = 0;
  for (int i = t; i < 16384; i += 256) bad |= (mw_[i] > 1u) ? 1u : 0u;
  if (bad) atomicOr(&s_flag, 1);
  __syncthreads();
  int flag = s_flag;
  if (b == 0 && t == 0) sm->flag_u8 = flag;

  int lane = t & 63, wid = t >> 6;
  int base = t * 16;
  const float* ab = alphas + b * SB + base;
  float av[16];
#pragma unroll
  for (int k = 0; k < 16; k += 4) {
    float4 v = *(const float4*)(ab + k);
    av[k] = v.x; av[k + 1] = v.y; av[k + 2] = v.z; av[k + 3] = v.w;
  }
  if (flag) {
    const unsigned char* mb = (const unsigned char*)mask + b * SB + base;
    uint4 mv = *(const uint4*)mb;
    unsigned mw[4] = {mv.x, mv.y, mv.z, mv.w};
#pragma unroll
    for (int k = 0; k < 16; ++k)
      if ((mw[k >> 2] >> ((k & 3) * 8)) & 0xFFu) av[k] = 0.f;
  } else {
    const int* mi = (const int*)mask + b * SB + base;
#pragma unroll
    for (int k = 0; k < 16; ++k)
      if (mi[k]) av[k] = 0.f;
  }
  float s = 0.f;
#pragma unroll
  for (int k = 0; k < 16; ++k) s += av[k];
  float si = s;
#pragma unroll
  for (int off = 1; off < 64; off <<= 1) {
    float v = __shfl_up(si, off);
    if (lane >= off) si += v;
  }
  __shared__ float wsum[4];
  if (lane == 63) wsum[wid] = si;
  __syncthreads();
  float woff = 0.f;
  for (int w = 0; w < wid; ++w) woff += wsum[w];
  float c = woff + (si - s);  // exclusive prefix
  float* cb = csum + b * SB + base;
#pragma unroll
  for (int k = 0; k < 16; ++k) { c += av[k]; cb[k] = c; }
  if (t == 255) {
    float total = woff + si;
    sm->fl_old[b] = (int)floorf(total);
  }
}

// K2: weights {lw, rw}, fire-position scatter S[b][r]=i (plain stores),
// tail reduction -> scale/fl_new/feat_lengths out.
__global__ void __launch_bounds__(256)
k_weights(const float* __restrict__ alphas, const void* __restrict__ mask,
          const float* __restrict__ csum, Small* sm,
          float2* __restrict__ wlr, int* __restrict__ S,
          float* __restrict__ out1, int T) {
  int b = blockIdx.x;
  int t = threadIdx.x;
  int flag = sm->flag_u8;
  int T0 = sm->fl_old[0];
#pragma unroll
  for (int j = 1; j < BB; ++j) T0 = max(T0, sm->fl_old[j]);
  int fl = sm->fl_old[b];
  int base = t * 16;
  int gbase = b * SB + base;

  float cs[16];
#pragma unroll
  for (int k = 0; k < 16; k += 4) {
    float4 v = *(const float4*)(csum + gbase + k);
    cs[k] = v.x; cs[k + 1] = v.y; cs[k + 2] = v.z; cs[k + 3] = v.w;
  }
  float cprev = (base == 0) ? 0.f : csum[gbase - 1];
  float av[16];
#pragma unroll
  for (int k = 0; k < 16; k += 4) {
    float4 v = *(const float4*)(alphas + gbase + k);
    av[k] = v.x; av[k + 1] = v.y; av[k + 2] = v.z; av[k + 3] = v.w;
  }
  unsigned mbits = 0;
  if (flag) {
    const unsigned char* mb = (const unsigned char*)mask + gbase;
    uint4 mv = *(const uint4*)mb;
    unsigned mw[4] = {mv.x, mv.y, mv.z, mv.w};
#pragma unroll
    for (int k = 0; k < 16; ++k)
      if ((mw[k >> 2] >> ((k & 3) * 8)) & 0xFFu) { av[k] = 0.f; mbits |= 1u << k; }
  } else {
    const int* mi = (const int*)mask + gbase;
#pragma unroll
    for (int k = 0; k < 16; ++k)
      if (mi[k]) { av[k] = 0.f; mbits |= 1u << k; }
  }

  int lmax = -1;
#pragma unroll
  for (int k = 0; k < 16; ++k) if (!((mbits >> k) & 1u)) lmax = base + k;

  float tc = 0.f;
  float2 w2[16];
  int   rr[16];
  unsigned fbits = 0;
  int p = (base == 0) ? 0 : min((int)rintf(cprev), T0);
#pragma unroll
  for (int k = 0; k < 16; ++k) {
    int r = min((int)rintf(cs[k]), T0);
    int fire = r - p;                       // in {0,1} for alphas < 1
    float rwv = (fire > 0) ? (cs[k] - (float)r) : 0.f;
    float lwv = av[k] - rwv;
    w2[k] = make_float2(lwv, rwv);
    rr[k] = r;
    if (fire > 0) fbits |= 1u << k;
    tc += ((r == fl) ? rwv : 0.f) + ((p == fl) ? lwv : 0.f);
    p = r;
  }
#pragma unroll
  for (int k = 0; k < 16; k += 2) {
    float4 st = make_float4(w2[k].x, w2[k].y, w2[k + 1].x, w2[k + 1].y);
    *(float4*)(wlr + gbase + k) = st;
  }

  for (int off = 32; off; off >>= 1) {
    lmax = max(lmax, __shfl_down(lmax, off));
    tc += __shfl_down(tc, off);
  }
  __shared__ int   redl[4];
  __shared__ float redt[4];
  int wid = t >> 6;
  if ((t & 63) == 0) { redl[wid] = lmax; redt[wid] = tc; }
  __syncthreads();
  int llast = max(max(redl[0], redl[1]), max(redl[2], redl[3]));

  int* Sb = S + b * (T + 2);
  for (int j = t; j < T + 2; j += 256) Sb[j] = (j == 0) ? 0 : llast;
  __syncthreads();
#pragma unroll
  for (int k = 0; k < 16; ++k)
    if ((fbits >> k) & 1u) Sb[rr[k]] = base + k;

  if (t == 0) {
    float tail = redt[0] + redt[1] + redt[2] + redt[3];
    int e = (tail >= 0.5f) ? 1 : 0;
    sm->scale[b] = e ? (1.0f / tail) : 1.0f;
    int fln = fl + e;
    sm->fl_new[b] = fln;
    out1[b] = (float)max(fln, 1);
  }
}

// K3: gather, RPB consecutive rows per block, chunked CH-deep load prefetch
// (maximize outstanding loads per wave); XCD-chunked bijective swizzle.
__global__ void __launch_bounds__(128)
k_gather(const float* __restrict__ src, const float2* __restrict__ wlr,
         const int* __restrict__ S, const Small* __restrict__ sm,
         float* __restrict__ out, int T, int nwgx, int q, int rmod) {
  int orig = blockIdx.x;
  int xcd = orig & 7;
  int idx = orig >> 3;
  int wg = ((xcd < rmod) ? xcd * (q + 1) : rmod * (q + 1) + (xcd - rmod) * q) + idx;
  int b  = wg / nwgx;
  int t0 = (wg - b * nwgx) * RPB;

  int tid = threadIdx.x;
  int fln = sm->fl_new[b];
  int flo = sm->fl_old[b];
  float sc = sm->scale[b];
  float* outb = out + ((size_t)b * T + t0) * CC;

  int nrows = T - t0; if (nrows > RPB) nrows = RPB;
  int nact = fln - t0; if (nact > RPB) nact = RPB; if (nact < 0) nact = 0;
  for (int j = nact; j < nrows; ++j)
    ((float4*)(outb + (size_t)j * CC))[tid] = make_float4(0.f, 0.f, 0.f, 0.f);
  if (nact <= 0) return;

  const int* Sb = S + b * (T + 2);
  int sarr[RPB + 1];
#pragma unroll
  for (int j = 0; j <= RPB; ++j) sarr[j] = (j <= nact) ? Sb[t0 + j] : 0x7FFFFFFF;

  int start = sarr[0];
  int end   = sarr[nact];
  const float* srcb = src + (size_t)b * SB * CC;
  const float2* wb  = wlr + b * SB;

  float4 acc[RPB];
#pragma unroll
  for (int j = 0; j < RPB; ++j) acc[j] = make_float4(0.f, 0.f, 0.f, 0.f);

  for (int c = start; c <= end; c += CH) {
    int nk = end - c + 1; if (nk > CH) nk = CH;
    float2 w2v[CH];
    float4 sv[CH];
    // issue all CH loads (clamped) before any use -> ~2*CH outstanding loads
#pragma unroll
    for (int k = 0; k < CH; ++k) {
      int i = (k < nk) ? (c + k) : end;
      w2v[k] = wb[i];
      sv[k]  = ((const float4*)(srcb + (size_t)i * CC))[tid];
    }
#pragma unroll
    for (int k = 0; k < CH; ++k) {
      if (k < nk) {
        int i = c + k;
#pragma unroll
        for (int j = 0; j < RPB; ++j) {
          if (j < nact) {
            bool inr = (i >= sarr[j]) && (i <= sarr[j + 1]);
            float w = (i == sarr[j] && (t0 + j) > 0) ? w2v[k].y : w2v[k].x;
            w = inr ? w : 0.f;
            acc[j].x = fmaf(w, sv[k].x, acc[j].x);
            acc[j].y = fmaf(w, sv[k].y, acc[j].y);
            acc[j].z = fmaf(w, sv[k].z, acc[j].z);
            acc[j].w = fmaf(w, sv[k].w, acc[j].w);
          }
        }
      }
    }
  }
#pragma unroll
  for (int j = 0; j < RPB; ++j) {
    if (j < nact) {
      float m = ((t0 + j) == flo) ? sc : 1.0f;
      float4 v = make_float4(acc[j].x * m, acc[j].y * m, acc[j].z * m, acc[j].w * m);
      ((float4*)(outb + (size_t)j * CC))[tid] = v;
    }
  }
}

extern "C" void kernel_launch(void* const* d_in, const int* in_sizes, int n_in,
                              void* d_out, int out_size, void* d_ws, size_t ws_size,
                              hipStream_t stream) {
  const float* src = (const float*)d_in[0];
  const void* mask = d_in[1];
  const float* alphas = (const float*)d_in[2];
  float* out = (float*)d_out;
  char* ws = (char*)d_ws;

  int T = (out_size - BB) / (BB * CC);

  float* csum = (float*)(ws + 0);          // 256 KB
  float2* wlr = (float2*)(ws + 262144);    // 512 KB
  int* S      = (int*)(ws + 786432);       // BB*(T+2)*4
  Small* sm   = (Small*)(ws + 1572864);

  k_scan<<<BB, 256, 0, stream>>>(alphas, mask, csum, sm);
  k_weights<<<BB, 256, 0, stream>>>(alphas, mask, csum, sm, wlr, S,
                                    out + (size_t)BB * T * CC, T);
  int nwgx = (T + RPB - 1) / RPB;
  int nwg = BB * nwgx;
  int q = nwg / 8, rmod = nwg % 8;
  k_gather<<<nwg, 128, 0, stream>>>(src, wlr, S, sm, out, T, nwgx, q, rmod);
}